// Round 18
// baseline (769.683 us; speedup 1.0000x reference)
//
#include <hip/hip_runtime.h>
#include <stddef.h>

#define EPS 1e-5f
#define N_HW 3136              // 56*56
#define G 32                   // full batch, single pass
#define NG (G * N_HW)          // 100352 = GEMM N dimension
#define DIMC 800
#define NTILE 49               // 3136/64: 64-col tiles per image

typedef unsigned short u16;
typedef __attribute__((ext_vector_type(8))) short short8;
typedef __attribute__((ext_vector_type(4))) float floatx4;

__device__ __forceinline__ u16 f2b(float f) {
  unsigned u = __float_as_uint(f);
  u += 0x7FFFu + ((u >> 16) & 1u);        // round-to-nearest-even
  return (u16)(u >> 16);
}
__device__ __forceinline__ float blo(unsigned u) { return __uint_as_float(u << 16); }
__device__ __forceinline__ float bhi(unsigned u) { return __uint_as_float(u & 0xFFFF0000u); }

// ---------------- ws layout (bytes) ----------------
// XA_kt : bf16 [19 tiles][NG][32kin] = 122,028,032  (k-major: B frag = 16B contig)
// buf1  : bf16 [192][NG] = 38,535,168  (layer blocks; stem h1/h2 alias inside)
// H0f   : f32  [32][NG]  = 12,845,056  (stem out f32 — bf16 here = 7x error, r16)
// gwb   : bf16 800x800; stats: 5 x 12288 f32; p16: f32 [192][32][16]
static const size_t XAKT_OFF = 0;
static const size_t BUF1_OFF = 122028032ull;
static const size_t H0F_OFF  = 160563200ull;
static const size_t GWB_OFF  = 173408256ull;
static const size_t STAT_OFF = 174688256ull;           // 5*12288*4 = 245,760
static const size_t P16_OFF  = 174934016ull;           // 393,216
static const size_t M4_OFF   = 175327232ull;
static const size_t MH_OFF   = M4_OFF + 6144 * 4;
static const size_t OP_OFF   = MH_OFF + 6144 * 4;
static const size_t NEED     = OP_OFF + 6144 * 4;      // ~175.4 MB (< 179.5 proven)

// ---------------- small utility kernels ----------------
__global__ __launch_bounds__(256) void gw2bf(const float* __restrict__ gw, u16* __restrict__ gwb) {
  int i = (blockIdx.x * 256 + threadIdx.x) * 4;   // 640000 elems, 625 blocks
  float4 v = *(const float4*)(gw + i);
  gwb[i + 0] = f2b(v.x); gwb[i + 1] = f2b(v.y);
  gwb[i + 2] = f2b(v.z); gwb[i + 3] = f2b(v.w);
}

__global__ __launch_bounds__(256) void zero_stats(float* __restrict__ p) {
  p[blockIdx.x * 256 + threadIdx.x] = 0.f;        // 61440 floats, 240 blocks
}

// ---------------- stem conv1: LDS-tiled, all 16 ch per block ----------------
#define XT_PITCH 226
#define XT_CH (17 * XT_PITCH)          // 3842
__global__ __launch_bounds__(256) void stem_conv1(
    const float* __restrict__ xg, const float* __restrict__ w, const float* __restrict__ b1,
    const float* __restrict__ g, const float* __restrict__ bb,
    const float* __restrict__ m, const float* __restrict__ v,
    float* __restrict__ h1) {
  __shared__ float xt[3 * XT_CH];      // 46.1 KB
  __shared__ float wt[16 * 27];
  __shared__ float mulc[16], addc[16];
  int blk = blockIdx.x;                // s + 14*bg
  int s = blk % 14;
  int bg = blk / 14;
  int tid = threadIdx.x;

  for (int e = tid; e < 432; e += 256) wt[e] = w[e];
  if (tid < 16) {
    float A = g[tid] * rsqrtf(v[tid] + EPS);
    mulc[tid] = A;
    addc[tid] = (b1[tid] - m[tid]) * A + bb[tid];
  }
  int iy0 = 16 * s - 1;
  for (int e = tid; e < 3 * XT_CH; e += 256) {
    int ci = e / XT_CH;
    int rem = e - ci * XT_CH;
    int r = rem / XT_PITCH;
    int cc = rem - r * XT_PITCH;
    int iy = iy0 + r, ix = cc - 1;
    float val = 0.f;
    if (iy >= 0 && iy < 224 && ix >= 0 && ix < 224)
      val = xg[((size_t)(bg * 3 + ci)) * 224 * 224 + iy * 224 + ix];
    xt[e] = val;
  }
  __syncthreads();

  for (int p = tid; p < 8 * 112; p += 256) {
    int oyl = p / 112, ox = p - oyl * 112;
    float xv[27];
#pragma unroll
    for (int ci = 0; ci < 3; ci++)
#pragma unroll
      for (int ky = 0; ky < 3; ky++)
#pragma unroll
        for (int kx = 0; kx < 3; kx++)
          xv[ci * 9 + ky * 3 + kx] = xt[ci * XT_CH + (2 * oyl + ky) * XT_PITCH + 2 * ox + kx];
    int oy = 8 * s + oyl;
#pragma unroll
    for (int c = 0; c < 16; c++) {
      float acc = 0.f;
#pragma unroll
      for (int t = 0; t < 27; t++) acc += xv[t] * wt[c * 27 + t];
      float y = acc * mulc[c] + addc[c];
      h1[(size_t)(c * G + bg) * 12544 + oy * 112 + ox] = fmaxf(y, 0.f);
    }
  }
}

__global__ __launch_bounds__(256) void stem_dw(
    const float* __restrict__ h1, const float* __restrict__ dw, const float* __restrict__ dwb,
    float* __restrict__ h2) {
  int idx = blockIdx.x * 256 + threadIdx.x;       // ((c*G)+bg)*3136 + q
  int q = idx % N_HW;
  int t = idx / N_HW;
  int bg = t & (G - 1);
  int c = t >> 5;
  int qy = q / 56, qx = q % 56;
  const float* plane = h1 + (size_t)(c * G + bg) * 12544;
  float acc = dwb[c];
#pragma unroll
  for (int ky = 0; ky < 3; ky++) {
    int iy = qy * 2 - 1 + ky;
    if (iy < 0 || iy >= 112) continue;
#pragma unroll
    for (int kx = 0; kx < 3; kx++) {
      int ix = qx * 2 - 1 + kx;
      if (ix < 0 || ix >= 112) continue;
      acc += plane[iy * 112 + ix] * dw[c * 9 + ky * 3 + kx];
    }
  }
  h2[idx] = acc;
}

// stem pw: one block per (o,bg) row; writes f32 H0 + wave-reduced stats atomics
__global__ __launch_bounds__(256) void stem_pw_v2(
    const float* __restrict__ h2, const float* __restrict__ w2, const float* __restrict__ b2,
    const float* __restrict__ g, const float* __restrict__ bb,
    const float* __restrict__ m, const float* __restrict__ v,
    float* __restrict__ H0, float* __restrict__ stat0) {
  int r = blockIdx.x;              // o*32 + bg, 1024 blocks
  int o = r >> 5, bg = r & 31;
  int tid = threadIdx.x;
  float w[16];
#pragma unroll
  for (int c = 0; c < 16; c++) w[c] = w2[o * 16 + c];
  float A = g[o] * rsqrtf(v[o] + EPS);
  float mul = A, add = bb[o] - m[o] * A;
  const float* h2r = h2 + (size_t)bg * N_HW;
  float* outp = H0 + (size_t)r * N_HW;
  float s = 0.f, s2 = 0.f;
  for (int q = tid; q < N_HW; q += 256) {
    float acc = b2[o];
#pragma unroll
    for (int c = 0; c < 16; c++) acc += w[c] * h2r[(size_t)c * G * N_HW + q];
    float y = acc * mul + add;
    outp[q] = y;
    s += y; s2 += y * y;
  }
#pragma unroll
  for (int o2 = 32; o2 > 0; o2 >>= 1) {
    s += __shfl_down(s, o2);
    s2 += __shfl_down(s2, o2);
  }
  if ((tid & 63) == 0) {
    atomicAdd(&stat0[r], s);
    atomicAdd(&stat0[6144 + r], s2);
  }
}

// ------- norm+relu+dw 3x3 -> k-major XA_kt; coalesced cooperative loads ------
// block = (bg, strip of 4 output rows, 32-channel group). T = float (L0) / u16.
template <typename T>
__global__ __launch_bounds__(256) void dw_kt(
    const T* __restrict__ in, const float* __restrict__ cdw,
    const float* __restrict__ in_g, const float* __restrict__ in_b,
    const float* __restrict__ stat, u16* __restrict__ XAkt,
    int cdwoff, int ngroups) {
  __shared__ float sm[32 * 350];     // ch stride 350 (row stride 58)
  __shared__ float ssc[32], ssh[32], swt[32 * 9];
  int blk = blockIdx.x;
  int grp = blk % ngroups;
  int t2 = blk / ngroups;
  int strip = t2 % 14;
  int bg = t2 / 14;
  int tid = threadIdx.x;
  if (tid < 32) {
    int cl = grp * 32 + tid;
    int c = cdwoff + cl;
    int sidx = cl * 32 + bg;
    float S = stat[sidx], Q = stat[6144 + sidx];
    float mean = S * (1.f / N_HW);
    float var = fmaxf(Q * (1.f / N_HW) - mean * mean, 0.f);
    float sc = in_g[c] * rsqrtf(var + EPS);
    ssc[tid] = sc;
    ssh[tid] = in_b[c] - mean * sc;
  }
  for (int e = tid; e < 288; e += 256)
    swt[e] = cdw[(size_t)(cdwoff + grp * 32) * 9 + e];
  __syncthreads();   // ssc/ssh ready before interior fill uses them

  int y0 = strip * 4;
  // halo zeros: edge cols for in-range rows; full rows when OOB
  if (tid < 192) {
    int ch = tid / 6, rr = tid % 6;
    int y = y0 - 1 + rr;
    float* dst = &sm[ch * 350 + rr * 58];
    if (y < 0 || y > 55) {
#pragma unroll
      for (int x = 0; x < 58; x++) dst[x] = 0.f;
    } else {
      dst[0] = 0.f; dst[57] = 0.f;
    }
  }
  // coalesced interior fill (norm+relu applied): contiguous 672B per channel
  if constexpr (sizeof(T) == 2) {
    for (int e = tid; e < 32 * 42; e += 256) {   // ch x (6 rows x 7 chunks of 8)
      int ch = e / 42, rem = e % 42;
      int rr = rem / 7, xx = rem % 7;
      int y = y0 - 1 + rr;
      if (y >= 0 && y <= 55) {
        float sc = ssc[ch], sh = ssh[ch];
        const u16* src = (const u16*)in + ((size_t)(grp * 32 + ch) * G + bg) * N_HW + y * 56 + xx * 8;
        uint4 u = *(const uint4*)src;
        float* d = &sm[ch * 350 + rr * 58 + 1 + xx * 8];
        d[0] = fmaxf(blo(u.x) * sc + sh, 0.f);
        d[1] = fmaxf(bhi(u.x) * sc + sh, 0.f);
        d[2] = fmaxf(blo(u.y) * sc + sh, 0.f);
        d[3] = fmaxf(bhi(u.y) * sc + sh, 0.f);
        d[4] = fmaxf(blo(u.z) * sc + sh, 0.f);
        d[5] = fmaxf(bhi(u.z) * sc + sh, 0.f);
        d[6] = fmaxf(blo(u.w) * sc + sh, 0.f);
        d[7] = fmaxf(bhi(u.w) * sc + sh, 0.f);
      }
    }
  } else {
    for (int e = tid; e < 32 * 84; e += 256) {   // ch x (6 rows x 14 chunks of 4)
      int ch = e / 84, rem = e % 84;
      int rr = rem / 14, xx = rem % 14;
      int y = y0 - 1 + rr;
      if (y >= 0 && y <= 55) {
        float sc = ssc[ch], sh = ssh[ch];
        const float* src = (const float*)in + ((size_t)(grp * 32 + ch) * G + bg) * N_HW + y * 56 + xx * 4;
        float4 vv = *(const float4*)src;
        float* d = &sm[ch * 350 + rr * 58 + 1 + xx * 4];
        d[0] = fmaxf(vv.x * sc + sh, 0.f);
        d[1] = fmaxf(vv.y * sc + sh, 0.f);
        d[2] = fmaxf(vv.z * sc + sh, 0.f);
        d[3] = fmaxf(vv.w * sc + sh, 0.f);
      }
    }
  }
  __syncthreads();

  size_t tilebase = ((size_t)(cdwoff >> 5) + grp) * NG;
  for (int e = tid; e < 896; e += 256) {   // (n in strip) x (kin8 chunk)
    int pos = e >> 2, k8 = e & 3;
    int ry = pos / 56, x = pos % 56;
    int y = y0 + ry;
    u16 outv[8];
#pragma unroll
    for (int j = 0; j < 8; j++) {
      int ch = k8 * 8 + j;
      const float* b = &sm[ch * 350 + ry * 58 + x];
      const float* w = &swt[ch * 9];
      float a = b[0] * w[0] + b[1] * w[1] + b[2] * w[2]
              + b[58] * w[3] + b[59] * w[4] + b[60] * w[5]
              + b[116] * w[6] + b[117] * w[7] + b[118] * w[8];
      outv[j] = f2b(a);
    }
    *(uint4*)(XAkt + (tilebase + (size_t)bg * N_HW + y * 56 + x) * 32 + k8 * 8) =
        *(const uint4*)outv;
  }
}

// ---------------- MFMA GEMM v3: TILE-PAIRED, B direct from k-major XA_kt ----
// Block j handles two 64-col tiles: same hw window in images bg=j/49 and bg+16.
// Grid 784 (3.06 blocks/CU) — halves the per-iteration latency floor exposure.
// A in LDS (15.4 KB, shared by both tiles); 24 MFMA/wave/iter.
// MODE 0: + bf16 C. MODE 1 (L3): + f32 4x4-patch spill.
template <int MODE>
__global__ __launch_bounds__(256) void gemm_v3(
    const u16* __restrict__ A, const u16* __restrict__ Bkt, u16* __restrict__ C,
    float* __restrict__ stat, float* __restrict__ p16, int K) {
  __shared__ u16 As[192][40];   // pitch 80 B
  int j = blockIdx.x;           // 0..783
  int n0 = j * 64;              // tile0 cols; tile1 = n0 + 16*3136
  int tid = threadIdx.x;
  int wave = tid >> 6, lane = tid & 63;
  int wm = wave >> 1, wn = wave & 1;
  int lg = lane >> 4, li = lane & 15;
  floatx4 acc0[6][2] = {}, acc1[6][2] = {};

  int ar = tid >> 2, ak = (tid & 3) * 8;
  const u16* Ag = A + (size_t)ar * DIMC + ak;
  const u16* Bg0 = Bkt + ((size_t)(n0 + wn * 32 + li)) * 32 + lg * 8;  // frag ni: +512
  const u16* Bg1 = Bg0 + (size_t)16 * N_HW * 32;

  int nt = K / 32;
  uint4 ra0 = *(const uint4*)(Ag);
  uint4 ra1 = *(const uint4*)(Ag + (size_t)64 * DIMC);
  uint4 ra2 = *(const uint4*)(Ag + (size_t)128 * DIMC);
  uint4 rb00 = *(const uint4*)(Bg0);
  uint4 rb01 = *(const uint4*)(Bg0 + 512);
  uint4 rb10 = *(const uint4*)(Bg1);
  uint4 rb11 = *(const uint4*)(Bg1 + 512);

  for (int t = 0; t < nt; t++) {
    *(uint4*)&As[ar][ak]       = ra0;
    *(uint4*)&As[ar + 64][ak]  = ra1;
    *(uint4*)&As[ar + 128][ak] = ra2;
    __syncthreads();
    uint4 nb00, nb01, nb10, nb11;
    bool pf = (t + 1 < nt);
    if (pf) {
      const u16* ag = Ag + (size_t)(t + 1) * 32;
      ra0 = *(const uint4*)(ag);
      ra1 = *(const uint4*)(ag + (size_t)64 * DIMC);
      ra2 = *(const uint4*)(ag + (size_t)128 * DIMC);
      size_t koff = (size_t)(t + 1) * NG * 32;
      nb00 = *(const uint4*)(Bg0 + koff);
      nb01 = *(const uint4*)(Bg0 + koff + 512);
      nb10 = *(const uint4*)(Bg1 + koff);
      nb11 = *(const uint4*)(Bg1 + koff + 512);
    }
    short8 aF[6];
#pragma unroll
    for (int mi = 0; mi < 6; mi++)
      aF[mi] = *(const short8*)&As[wm * 96 + mi * 16 + li][lg * 8];
    short8 b00 = *(short8*)&rb00, b01 = *(short8*)&rb01;
    short8 b10 = *(short8*)&rb10, b11 = *(short8*)&rb11;
#pragma unroll
    for (int mi = 0; mi < 6; mi++) {
      acc0[mi][0] = __builtin_amdgcn_mfma_f32_16x16x32_bf16(aF[mi], b00, acc0[mi][0], 0, 0, 0);
      acc0[mi][1] = __builtin_amdgcn_mfma_f32_16x16x32_bf16(aF[mi], b01, acc0[mi][1], 0, 0, 0);
      acc1[mi][0] = __builtin_amdgcn_mfma_f32_16x16x32_bf16(aF[mi], b10, acc1[mi][0], 0, 0, 0);
      acc1[mi][1] = __builtin_amdgcn_mfma_f32_16x16x32_bf16(aF[mi], b11, acc1[mi][1], 0, 0, 0);
    }
    __syncthreads();
    if (pf) { rb00 = nb00; rb01 = nb01; rb10 = nb10; rb11 = nb11; }
  }

  int bg = j / NTILE;           // tile0 image; tile1 = bg+16
  // stats epilogue (both tiles)
#pragma unroll
  for (int mi = 0; mi < 6; mi++) {
#pragma unroll
    for (int r = 0; r < 4; r++) {
      float sa = acc0[mi][0][r] + acc0[mi][1][r];
      float qa = acc0[mi][0][r] * acc0[mi][0][r] + acc0[mi][1][r] * acc0[mi][1][r];
      float sb = acc1[mi][0][r] + acc1[mi][1][r];
      float qb = acc1[mi][0][r] * acc1[mi][0][r] + acc1[mi][1][r] * acc1[mi][1][r];
#pragma unroll
      for (int msk = 1; msk < 16; msk <<= 1) {
        sa += __shfl_xor(sa, msk);
        qa += __shfl_xor(qa, msk);
        sb += __shfl_xor(sb, msk);
        qb += __shfl_xor(qb, msk);
      }
      if (li == 0) {
        int row = wm * 96 + mi * 16 + lg * 4 + r;
        atomicAdd(&stat[row * 32 + bg], sa);
        atomicAdd(&stat[6144 + row * 32 + bg], qa);
        atomicAdd(&stat[row * 32 + bg + 16], sb);
        atomicAdd(&stat[6144 + row * 32 + bg + 16], qb);
      }
    }
  }
  if constexpr (MODE == 0) {
#pragma unroll
    for (int mi = 0; mi < 6; mi++) {
#pragma unroll
      for (int ni = 0; ni < 2; ni++) {
        int row = wm * 96 + mi * 16 + lg * 4;   // C/D: col=lane&15, row=lg*4+r
        int col = n0 + wn * 32 + ni * 16 + li;
        u16* cp0 = C + (size_t)row * NG + col;
        u16* cp1 = cp0 + (size_t)16 * N_HW;
#pragma unroll
        for (int r = 0; r < 4; r++) {
          cp0[(size_t)r * NG] = f2b(acc0[mi][ni][r]);
          cp1[(size_t)r * NG] = f2b(acc1[mi][ni][r]);
        }
      }
    }
  } else {
#pragma unroll
    for (int ni = 0; ni < 2; ni++) {
      int col = n0 + wn * 32 + ni * 16 + li;
      int hw = col % 3136;
      int yy = hw / 56, xx = hw % 56;
      int dy = yy - 25, dx = xx - 25;
      if ((unsigned)dy < 4u && (unsigned)dx < 4u) {
#pragma unroll
        for (int mi = 0; mi < 6; mi++)
#pragma unroll
          for (int r = 0; r < 4; r++) {
            int row = wm * 96 + mi * 16 + lg * 4 + r;
            p16[((size_t)row * 32 + bg) * 16 + dy * 4 + dx] = acc0[mi][ni][r];
            p16[((size_t)row * 32 + bg + 16) * 16 + dy * 4 + dx] = acc1[mi][ni][r];
          }
      }
    }
  }
}

// ------- head: layer-4 norm + dwconv on 4x4 patch from stats + p16 ----------
__global__ __launch_bounds__(256) void head_m4(
    const float* __restrict__ stat4, const float* __restrict__ p16,
    const float* __restrict__ in_g, const float* __restrict__ in_b,
    const float* __restrict__ cdw, float* __restrict__ m4, float* __restrict__ meanH) {
  int idx = blockIdx.x * 256 + threadIdx.x;   // cl*32 + bg
  if (idx >= 192 * 32) return;
  int cl = idx >> 5;
  int c = 608 + cl;
  float S = stat4[idx], Q = stat4[6144 + idx];
  float mean = S * (1.f / N_HW);
  float var = fmaxf(Q * (1.f / N_HW) - mean * mean, 0.f);
  float sc = in_g[c] * rsqrtf(var + EPS);
  float sh = in_b[c] - mean * sc;
  const float* pf = p16 + (size_t)idx * 16;
  float val[4][4];
#pragma unroll
  for (int dy = 0; dy < 4; dy++)
#pragma unroll
    for (int dx = 0; dx < 4; dx++)
      val[dy][dx] = fmaxf(pf[dy * 4 + dx] * sc + sh, 0.f);
  const float* w = cdw + c * 9;
  float acc = 0.f;
#pragma unroll
  for (int oy = 1; oy < 3; oy++)
#pragma unroll
    for (int ox = 1; ox < 3; ox++)
#pragma unroll
      for (int ky = 0; ky < 3; ky++)
#pragma unroll
        for (int kx = 0; kx < 3; kx++)
          acc += val[oy + ky - 1][ox + kx - 1] * w[ky * 3 + kx];
  m4[idx] = acc * 0.25f;
  meanH[idx] = 0.25f * (pf[5] + pf[6] + pf[9] + pf[10]);
}

__global__ __launch_bounds__(256) void head_mix(
    const float* __restrict__ gw, const float* __restrict__ m4, const float* __restrict__ meanH,
    float* __restrict__ out_pre) {
  int idx = blockIdx.x * 256 + threadIdx.x;   // bg*192 + j
  if (idx >= G * 192) return;
  int j = idx % 192;
  int bg = idx / 192;
  float acc = meanH[j * G + bg];
  const float* grow = gw + (size_t)(608 + j) * DIMC + 608;
  for (int c = 0; c < 192; c++) acc += grow[c] * m4[c * G + bg];
  out_pre[idx] = acc;
}

__global__ __launch_bounds__(256) void head_fc(
    const float* __restrict__ out_pre, const float* __restrict__ fc_w,
    const float* __restrict__ fc_b, float* __restrict__ outg) {
  int idx = blockIdx.x * 256 + threadIdx.x;   // bg*1000 + t
  if (idx >= G * 1000) return;
  int t = idx % 1000;
  int bg = idx / 1000;
  float acc = fc_b[t];
  const float* wr = fc_w + (size_t)t * 192;
  const float* hr = out_pre + (size_t)bg * 192;
  for (int j = 0; j < 192; j++) acc += wr[j] * hr[j];
  outg[idx] = acc;
}

extern "C" void kernel_launch(void* const* d_in, const int* in_sizes, int n_in,
                              void* d_out, int out_size, void* d_ws, size_t ws_size,
                              hipStream_t stream) {
  const float* x      = (const float*)d_in[0];
  const float* ds_w1  = (const float*)d_in[1];
  const float* ds_b1  = (const float*)d_in[2];
  const float* bn1_g  = (const float*)d_in[3];
  const float* bn1_b  = (const float*)d_in[4];
  const float* bn1_m  = (const float*)d_in[5];
  const float* bn1_v  = (const float*)d_in[6];
  const float* ds_dw  = (const float*)d_in[7];
  const float* ds_dwb = (const float*)d_in[8];
  const float* ds_w2  = (const float*)d_in[9];
  const float* ds_b2  = (const float*)d_in[10];
  const float* bn2_g  = (const float*)d_in[11];
  const float* bn2_b  = (const float*)d_in[12];
  const float* bn2_m  = (const float*)d_in[13];
  const float* bn2_v  = (const float*)d_in[14];
  const float* cdw    = (const float*)d_in[15];
  const float* gw     = (const float*)d_in[16];
  const float* in_g   = (const float*)d_in[17];
  const float* in_b   = (const float*)d_in[18];
  const float* fc_w   = (const float*)d_in[19];
  const float* fc_b   = (const float*)d_in[20];
  float* out = (float*)d_out;
  char* ws = (char*)d_ws;

  if (ws_size < NEED) return;

  u16*   XAkt  = (u16*)(ws + XAKT_OFF);
  u16*   buf1  = (u16*)(ws + BUF1_OFF);
  float* H0f   = (float*)(ws + H0F_OFF);
  u16*   gwb   = (u16*)(ws + GWB_OFF);
  float* stats = (float*)(ws + STAT_OFF);           // 5 x 12288
  float* p16   = (float*)(ws + P16_OFF);
  float* m4    = (float*)(ws + M4_OFF);
  float* meanH = (float*)(ws + MH_OFF);
  float* opre  = (float*)(ws + OP_OFF);
  float* h1    = (float*)buf1;                      // 25.7 MB, dead after stem_dw
  float* h2    = h1 + (size_t)16 * G * 12544;       // 6.4 MB, inside buf1

  gw2bf<<<625, 256, 0, stream>>>(gw, gwb);
  zero_stats<<<240, 256, 0, stream>>>(stats);

  static const int CDWOFF[4] = {0, 32, 224, 416};   // dw layer channel base
  static const int NGRP[4]   = {1, 6, 6, 6};
  static const int RA[4]     = {32, 224, 416, 608}; // gemm output channel base
  static const int KK[4]     = {32, 224, 416, 608};

  stem_conv1<<<14 * G, 256, 0, stream>>>(
      x, ds_w1, ds_b1, bn1_g, bn1_b, bn1_m, bn1_v, h1);
  stem_dw<<<16 * G * N_HW / 256, 256, 0, stream>>>(h1, ds_dw, ds_dwb, h2);
  stem_pw_v2<<<1024, 256, 0, stream>>>(
      h2, ds_w2, ds_b2, bn2_g, bn2_b, bn2_m, bn2_v, H0f, stats /*stat0*/);

  for (int i = 0; i < 4; i++) {
    float* statIn  = stats + (size_t)i * 12288;       // input-block stats
    float* statOut = stats + (size_t)(i + 1) * 12288; // this gemm's output stats
    if (i == 0)
      dw_kt<float><<<32 * 14 * NGRP[i], 256, 0, stream>>>(
          H0f, cdw, in_g, in_b, statIn, XAkt, CDWOFF[i], NGRP[i]);
    else
      dw_kt<u16><<<32 * 14 * NGRP[i], 256, 0, stream>>>(
          buf1, cdw, in_g, in_b, statIn, XAkt, CDWOFF[i], NGRP[i]);
    if (i < 3)
      gemm_v3<0><<<NG / 128, 256, 0, stream>>>(
          gwb + (size_t)RA[i] * DIMC, XAkt, buf1, statOut, nullptr, KK[i]);
    else
      gemm_v3<1><<<NG / 128, 256, 0, stream>>>(
          gwb + (size_t)RA[i] * DIMC, XAkt, nullptr, statOut, p16, KK[i]);
  }

  head_m4<<<24, 256, 0, stream>>>(stats + 4 * 12288, p16, in_g, in_b, cdw, m4, meanH);
  head_mix<<<(G * 192 + 255) / 256, 256, 0, stream>>>(gw, m4, meanH, opre);
  head_fc<<<(G * 1000 + 255) / 256, 256, 0, stream>>>(opre, fc_w, fc_b, out);
}

// Round 19
// 387.664 us; speedup vs baseline: 1.9854x; 1.9854x over previous
//
#include <hip/hip_runtime.h>
#include <stddef.h>

#define EPS 1e-5f
#define N_HW 3136              // 56*56
#define G 32                   // full batch, single pass
#define NG (G * N_HW)          // 100352 = GEMM N dimension
#define DIMC 800
#define NTILE 49               // 3136/64: 64-col tiles per image

typedef unsigned short u16;
typedef __attribute__((ext_vector_type(8))) short short8;
typedef __attribute__((ext_vector_type(4))) float floatx4;

__device__ __forceinline__ u16 f2b(float f) {
  unsigned u = __float_as_uint(f);
  u += 0x7FFFu + ((u >> 16) & 1u);        // round-to-nearest-even
  return (u16)(u >> 16);
}
__device__ __forceinline__ float blo(unsigned u) { return __uint_as_float(u << 16); }
__device__ __forceinline__ float bhi(unsigned u) { return __uint_as_float(u & 0xFFFF0000u); }

// ---------------- ws layout (bytes) ----------------
static const size_t XA_OFF  = 0;
static const size_t H0_OFF  = 122028032ull;
static const size_t BLK_OFF = 134873088ull;
static const size_t GWB_OFF = 173408256ull;
static const size_t STS_OFF = 174688256ull;
static const size_t STQ_OFF = 174712832ull;
static const size_t PAT_OFF = 174737408ull;
static const size_t M4_OFF  = 179456000ull;
static const size_t MH_OFF  = M4_OFF + 6144 * 4;
static const size_t OP_OFF  = MH_OFF + 6144 * 4;
static const size_t NEED    = OP_OFF + 6144 * 4;   // ~179.5 MB

// ---------------- small utility kernels ----------------
__global__ __launch_bounds__(256) void gw2bf(const float* __restrict__ gw, u16* __restrict__ gwb) {
  int i = (blockIdx.x * 256 + threadIdx.x) * 4;   // 640000 elems, 625 blocks
  float4 v = *(const float4*)(gw + i);
  gwb[i + 0] = f2b(v.x); gwb[i + 1] = f2b(v.y);
  gwb[i + 2] = f2b(v.z); gwb[i + 3] = f2b(v.w);
}

__global__ __launch_bounds__(256) void zero_stats(float* __restrict__ p) {
  p[blockIdx.x * 256 + threadIdx.x] = 0.f;        // 12288 floats, 48 blocks
}

// ---------------- stem conv1: LDS-tiled, all 16 ch per block ----------------
#define XT_PITCH 226
#define XT_CH (17 * XT_PITCH)          // 3842
__global__ __launch_bounds__(256) void stem_conv1(
    const float* __restrict__ xg, const float* __restrict__ w, const float* __restrict__ b1,
    const float* __restrict__ g, const float* __restrict__ bb,
    const float* __restrict__ m, const float* __restrict__ v,
    float* __restrict__ h1) {
  __shared__ float xt[3 * XT_CH];      // 46.1 KB
  __shared__ float wt[16 * 27];
  __shared__ float mulc[16], addc[16];
  int blk = blockIdx.x;                // s + 14*bg
  int s = blk % 14;
  int bg = blk / 14;
  int tid = threadIdx.x;

  for (int e = tid; e < 432; e += 256) wt[e] = w[e];
  if (tid < 16) {
    float A = g[tid] * rsqrtf(v[tid] + EPS);
    mulc[tid] = A;
    addc[tid] = (b1[tid] - m[tid]) * A + bb[tid];
  }
  int iy0 = 16 * s - 1;
  for (int e = tid; e < 3 * XT_CH; e += 256) {
    int ci = e / XT_CH;
    int rem = e - ci * XT_CH;
    int r = rem / XT_PITCH;
    int cc = rem - r * XT_PITCH;
    int iy = iy0 + r, ix = cc - 1;
    float val = 0.f;
    if (iy >= 0 && iy < 224 && ix >= 0 && ix < 224)
      val = xg[((size_t)(bg * 3 + ci)) * 224 * 224 + iy * 224 + ix];
    xt[e] = val;
  }
  __syncthreads();

  for (int p = tid; p < 8 * 112; p += 256) {
    int oyl = p / 112, ox = p - oyl * 112;
    float xv[27];
#pragma unroll
    for (int ci = 0; ci < 3; ci++)
#pragma unroll
      for (int ky = 0; ky < 3; ky++)
#pragma unroll
        for (int kx = 0; kx < 3; kx++)
          xv[ci * 9 + ky * 3 + kx] = xt[ci * XT_CH + (2 * oyl + ky) * XT_PITCH + 2 * ox + kx];
    int oy = 8 * s + oyl;
#pragma unroll
    for (int c = 0; c < 16; c++) {
      float acc = 0.f;
#pragma unroll
      for (int t = 0; t < 27; t++) acc += xv[t] * wt[c * 27 + t];
      float y = acc * mulc[c] + addc[c];
      h1[(size_t)(c * G + bg) * 12544 + oy * 112 + ox] = fmaxf(y, 0.f);
    }
  }
}

__global__ __launch_bounds__(256) void stem_dw(
    const float* __restrict__ h1, const float* __restrict__ dw, const float* __restrict__ dwb,
    float* __restrict__ h2) {
  int idx = blockIdx.x * 256 + threadIdx.x;       // ((c*G)+bg)*3136 + q
  int q = idx % N_HW;
  int t = idx / N_HW;
  int bg = t & (G - 1);
  int c = t >> 5;
  int qy = q / 56, qx = q % 56;
  const float* plane = h1 + (size_t)(c * G + bg) * 12544;
  float acc = dwb[c];
#pragma unroll
  for (int ky = 0; ky < 3; ky++) {
    int iy = qy * 2 - 1 + ky;
    if (iy < 0 || iy >= 112) continue;
#pragma unroll
    for (int kx = 0; kx < 3; kx++) {
      int ix = qx * 2 - 1 + kx;
      if (ix < 0 || ix >= 112) continue;
      acc += plane[iy * 112 + ix] * dw[c * 9 + ky * 3 + kx];
    }
  }
  h2[idx] = acc;
}

__global__ __launch_bounds__(256) void stem_pw(
    const float* __restrict__ h2, const float* __restrict__ w2, const float* __restrict__ b2,
    const float* __restrict__ g, const float* __restrict__ bb,
    const float* __restrict__ m, const float* __restrict__ v,
    float* __restrict__ H0) {
  int idx = blockIdx.x * 256 + threadIdx.x;       // ((o*G)+bg)*3136 + q
  int q = idx % N_HW;
  int t = idx / N_HW;
  int bg = t & (G - 1);
  int o = t >> 5;
  float acc = b2[o];
#pragma unroll
  for (int c = 0; c < 16; c++) acc += w2[o * 16 + c] * h2[(size_t)(c * G + bg) * N_HW + q];
  float y = (acc - m[o]) * (g[o] * rsqrtf(v[o] + EPS)) + bb[o];
  H0[idx] = y;
}

// ------- fused instance-norm stats + norm + relu + depthwise 3x3 (pad 1) -------
template <typename T>
__global__ __launch_bounds__(256) void dw_fused(
    const T* __restrict__ base, const float* __restrict__ cdw,
    const float* __restrict__ in_g, const float* __restrict__ in_b,
    u16* __restrict__ XA, int cdwoff) {
  __shared__ float sm[58 * 58];
  __shared__ float wred[8];
  int blk = blockIdx.x;            // cl*G + bg
  int cl = blk >> 5;
  int c = cdwoff + cl;
  int tid = threadIdx.x;

  // halo-only zero init (rows 0,57; cols 0,57 of rows 1..56)
  if (tid < 58) { sm[tid] = 0.f; sm[57 * 58 + tid] = 0.f; }
  if (tid >= 64 && tid < 120) { int r = tid - 63; sm[r * 58] = 0.f; sm[r * 58 + 57] = 0.f; }

  const T* row = base + (size_t)blk * N_HW;
  float s = 0.f, s2 = 0.f;
  for (int i = tid; i < 392; i += 256) {
    float vals[8];
    if constexpr (sizeof(T) == 2) {
      uint4 u = *(const uint4*)((const u16*)row + i * 8);
      vals[0] = blo(u.x); vals[1] = bhi(u.x);
      vals[2] = blo(u.y); vals[3] = bhi(u.y);
      vals[4] = blo(u.z); vals[5] = bhi(u.z);
      vals[6] = blo(u.w); vals[7] = bhi(u.w);
    } else {
      float4 v0 = *(const float4*)((const float*)row + i * 8);
      float4 v1 = *(const float4*)((const float*)row + i * 8 + 4);
      vals[0] = v0.x; vals[1] = v0.y; vals[2] = v0.z; vals[3] = v0.w;
      vals[4] = v1.x; vals[5] = v1.y; vals[6] = v1.z; vals[7] = v1.w;
    }
    int p = i * 8;
    int y = p / 56, x = p - y * 56;
    float* d = &sm[(y + 1) * 58 + x + 1];
#pragma unroll
    for (int e = 0; e < 8; e++) {
      d[e] = vals[e];
      s += vals[e];
      s2 += vals[e] * vals[e];
    }
  }
#pragma unroll
  for (int o = 32; o > 0; o >>= 1) {
    s += __shfl_down(s, o);
    s2 += __shfl_down(s2, o);
  }
  if ((tid & 63) == 0) { wred[(tid >> 6) * 2] = s; wred[(tid >> 6) * 2 + 1] = s2; }
  __syncthreads();
  float ts = (wred[0] + wred[2]) + (wred[4] + wred[6]);
  float tq = (wred[1] + wred[3]) + (wred[5] + wred[7]);
  float mean = ts * (1.f / N_HW);
  float var = fmaxf(tq * (1.f / N_HW) - mean * mean, 0.f);
  float sc = in_g[c] * rsqrtf(var + EPS);
  float sh = in_b[c] - mean * sc;

  for (int i = tid; i < N_HW; i += 256) {
    int y = i / 56, x = i - y * 56;
    int pos = (y + 1) * 58 + x + 1;
    sm[pos] = fmaxf(sm[pos] * sc + sh, 0.f);
  }
  __syncthreads();

  float w0 = cdw[c * 9 + 0], w1 = cdw[c * 9 + 1], w2 = cdw[c * 9 + 2];
  float w3 = cdw[c * 9 + 3], w4 = cdw[c * 9 + 4], w5 = cdw[c * 9 + 5];
  float w6 = cdw[c * 9 + 6], w7 = cdw[c * 9 + 7], w8 = cdw[c * 9 + 8];
  u16* outp = XA + (size_t)blk * N_HW;
  for (int pp = tid; pp < N_HW / 2; pp += 256) {   // pairs (56 even -> same row)
    int p = pp * 2;
    int y = p / 56, x = p - y * 56;
    const float* p0 = &sm[y * 58 + x];
    float a0 = p0[0] * w0 + p0[1] * w1 + p0[2] * w2
             + p0[58] * w3 + p0[59] * w4 + p0[60] * w5
             + p0[116] * w6 + p0[117] * w7 + p0[118] * w8;
    float a1 = p0[1] * w0 + p0[2] * w1 + p0[3] * w2
             + p0[59] * w3 + p0[60] * w4 + p0[61] * w5
             + p0[117] * w6 + p0[118] * w7 + p0[119] * w8;
    unsigned pk = (unsigned)f2b(a0) | ((unsigned)f2b(a1) << 16);
    *(unsigned*)&outp[p] = pk;
  }
}

// ---------------- MFMA GEMM: C[192][NG] = A[192][K] @ B[K][NG] ----------------
// r14 structure (best measured): double-buffered LDS, depth-2 B prefetch,
// one barrier per K-tile + XCD-bijective grid swizzle (T1): each XCD works a
// contiguous 196-block B range for L2 locality. grid 1568 % 8 == 0 (bijective).
// MODE 0: store bf16 C.  MODE 1 (L3): per-row stats atomics + f32 patch spill.
template <int MODE>
__global__ __launch_bounds__(256) void gemm_mfma(
    const u16* __restrict__ A, const u16* __restrict__ B, u16* __restrict__ C,
    float* __restrict__ statS, float* __restrict__ statQ, float* __restrict__ patchf,
    int K) {
  __shared__ u16 As[2][192][40];   // pitch 80 B
  __shared__ u16 Bs[2][32][64];    // pitch 128 B, XOR-16 column swizzle
  // T1: bijective XCD swizzle (gridDim.x % 8 == 0)
  int nwg = gridDim.x;
  int cpx = nwg >> 3;                       // blocks per XCD chunk
  int j = (blockIdx.x & 7) * cpx + (blockIdx.x >> 3);
  int n0 = j * 64;
  int tid = threadIdx.x;
  int wave = tid >> 6, lane = tid & 63;
  int wm = wave >> 1, wn = wave & 1;
  int lg = lane >> 4, li = lane & 15;
  floatx4 acc[6][2] = {};

  int ar = tid >> 2, ak = (tid & 3) * 8;
  int bk = tid >> 3, bn = (tid & 7) * 8;
  int bnx = bn ^ ((bk >> 3) << 4);
  const u16* Ag = A + (size_t)ar * DIMC + ak;
  const u16* Bg = B + (size_t)bk * NG + n0 + bn;

  int nt = K / 32;
  // prologue: A(0) depth-1; B depth-2 (B(0) to write now, B(1) in flight)
  uint4 ra0 = *(const uint4*)(Ag);
  uint4 ra1 = *(const uint4*)(Ag + (size_t)64 * DIMC);
  uint4 ra2 = *(const uint4*)(Ag + (size_t)128 * DIMC);
  uint4 rb_w = *(const uint4*)(Bg);
  uint4 rb_f = (nt > 1) ? *(const uint4*)(Bg + (size_t)32 * NG) : rb_w;

  for (int t = 0; t < nt; t++) {
    int cur = t & 1;
    *(uint4*)&As[cur][ar][ak]       = ra0;
    *(uint4*)&As[cur][ar + 64][ak]  = ra1;
    *(uint4*)&As[cur][ar + 128][ak] = ra2;
    *(uint4*)&Bs[cur][bk][bnx]      = rb_w;
    uint4 rb_new;
    bool pfA = (t + 1 < nt);
    bool pfB = (t + 2 < nt);
    if (pfA) {                                  // A(t+1): 1 phase slack (L2)
      const u16* ag = Ag + (size_t)(t + 1) * 32;
      ra0 = *(const uint4*)(ag);
      ra1 = *(const uint4*)(ag + (size_t)64 * DIMC);
      ra2 = *(const uint4*)(ag + (size_t)128 * DIMC);
    }
    if (pfB)                                    // B(t+2): 2 phases slack (L3)
      rb_new = *(const uint4*)(Bg + (size_t)(t + 2) * 32 * NG);
    __syncthreads();
    short8 aF[6];
#pragma unroll
    for (int mi = 0; mi < 6; mi++)
      aF[mi] = *(const short8*)&As[cur][wm * 96 + mi * 16 + li][lg * 8];
#pragma unroll
    for (int ni = 0; ni < 2; ni++) {
      int colx = ((wn * 32 + ni * 16) ^ (lg << 4)) + li;
      short8 bF;
#pragma unroll
      for (int e = 0; e < 8; e++) bF[e] = (short)Bs[cur][lg * 8 + e][colx];
#pragma unroll
      for (int mi = 0; mi < 6; mi++)
        acc[mi][ni] = __builtin_amdgcn_mfma_f32_16x16x32_bf16(aF[mi], bF, acc[mi][ni], 0, 0, 0);
    }
    __syncthreads();                            // all reads done before next write
    rb_w = rb_f;
    if (pfB) rb_f = rb_new;
  }

  if constexpr (MODE == 0) {
#pragma unroll
    for (int mi = 0; mi < 6; mi++) {
#pragma unroll
      for (int ni = 0; ni < 2; ni++) {
        int row = wm * 96 + mi * 16 + lg * 4;   // C/D: col=lane&15, row=lg*4+r
        int col = n0 + wn * 32 + ni * 16 + li;
        u16* cp = C + (size_t)row * NG + col;
#pragma unroll
        for (int r = 0; r < 4; r++) cp[(size_t)r * NG] = f2b(acc[mi][ni][r]);
      }
    }
  } else {
    int bg = j / NTILE;
    int tile = j % NTILE;
#pragma unroll
    for (int mi = 0; mi < 6; mi++) {
#pragma unroll
      for (int r = 0; r < 4; r++) {
        float v0 = acc[mi][0][r], v1 = acc[mi][1][r];
        float s = v0 + v1;
        float q = v0 * v0 + v1 * v1;
#pragma unroll
        for (int msk = 1; msk < 16; msk <<= 1) {
          s += __shfl_xor(s, msk);
          q += __shfl_xor(q, msk);
        }
        if (li == 0) {
          int row = wm * 96 + mi * 16 + lg * 4 + r;
          atomicAdd(&statS[row * 32 + bg], s);
          atomicAdd(&statQ[row * 32 + bg], q);
        }
      }
    }
    if (tile >= 22 && tile <= 24) {
#pragma unroll
      for (int mi = 0; mi < 6; mi++) {
#pragma unroll
        for (int ni = 0; ni < 2; ni++) {
          int row = wm * 96 + mi * 16 + lg * 4;
          int pc = (tile - 22) * 64 + wn * 32 + ni * 16 + li;
#pragma unroll
          for (int r = 0; r < 4; r++)
            patchf[((size_t)(row + r) * 32 + bg) * 192 + pc] = acc[mi][ni][r];
        }
      }
    }
  }
}

// ------- head: layer-4 norm + dwconv on patch, stats from GEMM epilogue -------
__global__ __launch_bounds__(256) void head_m4(
    const float* __restrict__ statS, const float* __restrict__ statQ,
    const float* __restrict__ patchf,
    const float* __restrict__ in_g, const float* __restrict__ in_b,
    const float* __restrict__ cdw, float* __restrict__ m4, float* __restrict__ meanH) {
  int idx = blockIdx.x * 256 + threadIdx.x;   // cl*32 + bg
  if (idx >= 192 * 32) return;
  int cl = idx >> 5;
  int c = 608 + cl;
  float mean = statS[idx] * (1.f / N_HW);
  float var = fmaxf(statQ[idx] * (1.f / N_HW) - mean * mean, 0.f);
  float sc = in_g[c] * rsqrtf(var + EPS);
  float sh = in_b[c] - mean * sc;
  const float* pf = patchf + (size_t)idx * 192;
  float val[4][4];
#pragma unroll
  for (int dy = 0; dy < 4; dy++)
#pragma unroll
    for (int dx = 0; dx < 4; dx++) {
      int hw = (25 + dy) * 56 + 25 + dx;
      float v = pf[((hw >> 6) - 22) * 64 + (hw & 63)];
      val[dy][dx] = fmaxf(v * sc + sh, 0.f);
    }
  const float* w = cdw + c * 9;
  float acc = 0.f;
#pragma unroll
  for (int oy = 1; oy < 3; oy++)
#pragma unroll
    for (int ox = 1; ox < 3; ox++)
#pragma unroll
      for (int ky = 0; ky < 3; ky++)
#pragma unroll
        for (int kx = 0; kx < 3; kx++)
          acc += val[oy + ky - 1][ox + kx - 1] * w[ky * 3 + kx];
  m4[idx] = acc * 0.25f;
  float mh = 0.f;
#pragma unroll
  for (int dy = 0; dy < 2; dy++)
#pragma unroll
    for (int dx = 0; dx < 2; dx++) {
      int hw = (26 + dy) * 56 + 26 + dx;
      mh += pf[((hw >> 6) - 22) * 64 + (hw & 63)];
    }
  meanH[idx] = mh * 0.25f;
}

__global__ __launch_bounds__(256) void head_mix(
    const float* __restrict__ gw, const float* __restrict__ m4, const float* __restrict__ meanH,
    float* __restrict__ out_pre) {
  int idx = blockIdx.x * 256 + threadIdx.x;   // bg*192 + j
  if (idx >= G * 192) return;
  int j = idx % 192;
  int bg = idx / 192;
  float acc = meanH[j * G + bg];
  const float* grow = gw + (size_t)(608 + j) * DIMC + 608;
  for (int c = 0; c < 192; c++) acc += grow[c] * m4[c * G + bg];
  out_pre[idx] = acc;
}

__global__ __launch_bounds__(256) void head_fc(
    const float* __restrict__ out_pre, const float* __restrict__ fc_w,
    const float* __restrict__ fc_b, float* __restrict__ outg) {
  int idx = blockIdx.x * 256 + threadIdx.x;   // bg*1000 + t
  if (idx >= G * 1000) return;
  int t = idx % 1000;
  int bg = idx / 1000;
  float acc = fc_b[t];
  const float* wr = fc_w + (size_t)t * 192;
  const float* hr = out_pre + (size_t)bg * 192;
  for (int j = 0; j < 192; j++) acc += wr[j] * hr[j];
  outg[idx] = acc;
}

extern "C" void kernel_launch(void* const* d_in, const int* in_sizes, int n_in,
                              void* d_out, int out_size, void* d_ws, size_t ws_size,
                              hipStream_t stream) {
  const float* x      = (const float*)d_in[0];
  const float* ds_w1  = (const float*)d_in[1];
  const float* ds_b1  = (const float*)d_in[2];
  const float* bn1_g  = (const float*)d_in[3];
  const float* bn1_b  = (const float*)d_in[4];
  const float* bn1_m  = (const float*)d_in[5];
  const float* bn1_v  = (const float*)d_in[6];
  const float* ds_dw  = (const float*)d_in[7];
  const float* ds_dwb = (const float*)d_in[8];
  const float* ds_w2  = (const float*)d_in[9];
  const float* ds_b2  = (const float*)d_in[10];
  const float* bn2_g  = (const float*)d_in[11];
  const float* bn2_b  = (const float*)d_in[12];
  const float* bn2_m  = (const float*)d_in[13];
  const float* bn2_v  = (const float*)d_in[14];
  const float* cdw    = (const float*)d_in[15];
  const float* gw     = (const float*)d_in[16];
  const float* in_g   = (const float*)d_in[17];
  const float* in_b   = (const float*)d_in[18];
  const float* fc_w   = (const float*)d_in[19];
  const float* fc_b   = (const float*)d_in[20];
  float* out = (float*)d_out;
  char* ws = (char*)d_ws;

  if (ws_size < NEED) return;

  u16*   XAc    = (u16*)(ws + XA_OFF);
  float* H0     = (float*)(ws + H0_OFF);
  u16*   blockb = (u16*)(ws + BLK_OFF);
  u16*   gwb    = (u16*)(ws + GWB_OFF);
  float* statS  = (float*)(ws + STS_OFF);
  float* statQ  = (float*)(ws + STQ_OFF);
  float* patchf = (float*)(ws + PAT_OFF);
  float* m4     = (float*)(ws + M4_OFF);
  float* meanH  = (float*)(ws + MH_OFF);
  float* opre   = (float*)(ws + OP_OFF);
  float* h1     = (float*)(ws + BLK_OFF);           // stem temps alias blockb
  float* h2     = h1 + (size_t)16 * G * 12544;

  gw2bf<<<625, 256, 0, stream>>>(gw, gwb);
  zero_stats<<<48, 256, 0, stream>>>(statS);        // statS+statQ contiguous

  static const int CDWOFF[4] = {0, 32, 224, 416};   // dw layer channel base
  static const int SZ[4]     = {32, 192, 192, 192};
  static const int RA[4]     = {32, 224, 416, 608}; // gemm output channel base
  static const int KK[4]     = {32, 224, 416, 608};

  stem_conv1<<<14 * G, 256, 0, stream>>>(
      x, ds_w1, ds_b1, bn1_g, bn1_b, bn1_m, bn1_v, h1);
  stem_dw<<<16 * G * N_HW / 256, 256, 0, stream>>>(h1, ds_dw, ds_dwb, h2);
  stem_pw<<<32 * G * N_HW / 256, 256, 0, stream>>>(
      h2, ds_w2, ds_b2, bn2_g, bn2_b, bn2_m, bn2_v, H0);

  for (int i = 0; i < 4; i++) {
    if (i == 0)
      dw_fused<float><<<SZ[i] * G, 256, 0, stream>>>(
          H0, cdw, in_g, in_b, XAc + (size_t)CDWOFF[i] * NG, CDWOFF[i]);
    else
      dw_fused<u16><<<SZ[i] * G, 256, 0, stream>>>(
          blockb, cdw, in_g, in_b, XAc + (size_t)CDWOFF[i] * NG, CDWOFF[i]);
    if (i < 3)
      gemm_mfma<0><<<NG / 64, 256, 0, stream>>>(
          gwb + (size_t)RA[i] * DIMC, XAc, blockb, nullptr, nullptr, nullptr, KK[i]);
    else
      gemm_mfma<1><<<NG / 64, 256, 0, stream>>>(
          gwb + (size_t)RA[i] * DIMC, XAc, nullptr, statS, statQ, patchf, KK[i]);
  }

  head_m4<<<24, 256, 0, stream>>>(statS, statQ, patchf, in_g, in_b, cdw, m4, meanH);
  head_mix<<<(G * 192 + 255) / 256, 256, 0, stream>>>(gw, m4, meanH, opre);
  head_fc<<<(G * 1000 + 255) / 256, 256, 0, stream>>>(opre, fc_w, fc_b, out);
}